// Round 1
// baseline (442.909 us; speedup 1.0000x reference)
//
#include <hip/hip_runtime.h>

#define BB 128
#define DD 8732
#define MM 32
#define CC 21

constexpr int K1_PR  = 4;                               // priors per thread
constexpr int K1_CH  = 256 * K1_PR;                     // 1024 priors per block
constexpr int K1_NCH = (DD + K1_CH - 1) / K1_CH;        // 9 chunks
constexpr int K2_CELLS = 256;
constexpr int K2_NBLK  = (DD + K2_CELLS - 1) / K2_CELLS; // 35 blocks per row
constexpr int K2T_PER  = (DD + K2_CELLS - 1) / K2_CELLS; // 35 keys/thread in tail

// ---- workspace layout (bytes) ----
constexpr size_t WS_DPG    = 0;                          // B*M u64 atomicMax keys (32768 B)
constexpr size_t WS_ROW    = 32768;                      // B rows * 64 B: [0]=conf f32, [1]=loc f32, [2]=npos i32
constexpr int    ROW_STRIDE = 16;                        // floats per row slot (64 B)
constexpr size_t WS_GSUM   = 40960;                      // f32, own line
constexpr size_t WS_GNPOS  = 41088;                      // i32, own line
constexpr size_t WS_DONE   = 41216;                      // u32, own line
constexpr size_t WS_RDONE  = 41344;                      // B u32 per-row arrival counters (512 B)
constexpr size_t WS_ZERO_BYTES = 41856;                  // memset region
constexpr size_t WS_PACKED = 41984;                      // B*D u32 (lab<<8|bm)
constexpr size_t WS_CENEG  = WS_PACKED + (size_t)BB * DD * 4; // B*D f32

__device__ __forceinline__ float wave_sum_f(float v) {
#pragma unroll
  for (int o = 32; o > 0; o >>= 1) v += __shfl_xor(v, o, 64);
  return v;
}
__device__ __forceinline__ int wave_sum_i(int v) {
#pragma unroll
  for (int o = 32; o > 0; o >>= 1) v += __shfl_xor(v, o, 64);
  return v;
}

// ---------------- K1: matching ----------------
__global__ __launch_bounds__(256) void k1_match(
    const float* __restrict__ gt_boxes, const int* __restrict__ gt_labels,
    const float* __restrict__ dboxes,
    unsigned int* __restrict__ packed, unsigned long long* __restrict__ dpg) {
  __shared__ float s_gx1[MM], s_gy1[MM], s_gx2[MM], s_gy2[MM], s_ga[MM];
  __shared__ int s_gl[MM];
  __shared__ unsigned long long s_pm[MM * 4];

  const int b = blockIdx.y;
  const int tid = threadIdx.x;
  if (tid < MM) {
    const float* g = gt_boxes + ((size_t)b * MM + tid) * 4;
    const float x1 = g[0], y1 = g[1], x2 = g[2], y2 = g[3];
    s_gx1[tid] = x1; s_gy1[tid] = y1; s_gx2[tid] = x2; s_gy2[tid] = y2;
    s_ga[tid] = __fmul_rn(__fsub_rn(x2, x1), __fsub_rn(y2, y1));
    s_gl[tid] = gt_labels[b * MM + tid];
  }
  __syncthreads();

  float px1[K1_PR], py1[K1_PR], px2[K1_PR], py2[K1_PR], pa[K1_PR];
  int dd[K1_PR];
  const int dbase = blockIdx.x * K1_CH + tid;
#pragma unroll
  for (int i = 0; i < K1_PR; ++i) {
    const int d = dbase + i * 256;
    if (d < DD) {
      const float4 p = *(const float4*)(dboxes + (size_t)d * 4);
      const float hw = __fmul_rn(p.z, 0.5f), hh = __fmul_rn(p.w, 0.5f);
      px1[i] = __fsub_rn(p.x, hw); py1[i] = __fsub_rn(p.y, hh);
      px2[i] = __fadd_rn(p.x, hw); py2[i] = __fadd_rn(p.y, hh);
      pa[i] = __fmul_rn(__fsub_rn(px2[i], px1[i]), __fsub_rn(py2[i], py1[i]));
      dd[i] = d;
    } else {  // pad: iou=0, can never win ties (huge d)
      px1[i] = 3e9f; py1[i] = 3e9f; px2[i] = 3e9f; py2[i] = 3e9f; pa[i] = 1.0f;
      dd[i] = 0x7FFFFFFF;
    }
  }

  float vb[K1_PR]; int mb[K1_PR];
#pragma unroll
  for (int i = 0; i < K1_PR; ++i) { vb[i] = -1.0f; mb[i] = 0; }

  const int lane = tid & 63, wid = tid >> 6;
  for (int m = 0; m < MM; ++m) {
    const float gx1 = s_gx1[m], gy1 = s_gy1[m], gx2 = s_gx2[m], gy2 = s_gy2[m];
    const float ga = s_ga[m];
    float mv = -1.0f; int md = 0x7FFFFFFF;
#pragma unroll
    for (int i = 0; i < K1_PR; ++i) {
      // exact (non-contracted) f32 to match numpy bit-for-bit
      const float w = fmaxf(0.0f, __fsub_rn(fminf(gx2, px2[i]), fmaxf(gx1, px1[i])));
      const float h = fmaxf(0.0f, __fsub_rn(fminf(gy2, py2[i]), fmaxf(gy1, py1[i])));
      const float inter = __fmul_rn(w, h);
      const float den = __fsub_rn(__fadd_rn(ga, pa[i]), inter);
      const float val = __fdiv_rn(inter, den);
      if (val > vb[i]) { vb[i] = val; mb[i] = m; }   // strict >: first m wins
      if (val > mv) { mv = val; md = dd[i]; }        // d ascending: first d wins
    }
    // split reduction: f32-max butterfly, then min-d among exact-max ties
    float mva = mv;
#pragma unroll
    for (int o = 32; o > 0; o >>= 1) mva = fmaxf(mva, __shfl_xor(mva, o, 64));
    int mdm = (mv == mva) ? md : 0x7FFFFFFF;
#pragma unroll
    for (int o = 32; o > 0; o >>= 1) mdm = min(mdm, __shfl_xor(mdm, o, 64));
    if (lane == 0)
      s_pm[m * 4 + wid] =
          (((unsigned long long)__float_as_uint(mva)) << 32) |
          (unsigned long long)(0xFFFFFFFFu - (unsigned)mdm);
  }
  __syncthreads();
  if (tid < MM) {
    unsigned long long k0 = s_pm[tid * 4 + 0];
    if (s_pm[tid * 4 + 1] > k0) k0 = s_pm[tid * 4 + 1];
    if (s_pm[tid * 4 + 2] > k0) k0 = s_pm[tid * 4 + 2];
    if (s_pm[tid * 4 + 3] > k0) k0 = s_pm[tid * 4 + 3];
    atomicMax(&dpg[b * MM + tid], k0);
  }
#pragma unroll
  for (int i = 0; i < K1_PR; ++i) {
    if (dd[i] < DD) {
      const int lab = (vb[i] < 0.5f) ? 0 : s_gl[mb[i]];
      packed[(size_t)b * DD + dd[i]] = ((unsigned)lab << 8) | (unsigned)mb[i];
    }
  }
}

// LDS reused between CE staging (cls) and tail radix-select (r)
union K2Shared {
  float cls[K2_CELLS * CC];
  float4 cls4[(K2_CELLS * CC) / 4];
  struct { int hist[16 * 256]; int bin[256]; int sel[2]; } r;
};

// ---- K2 fused: CE + loc + n_pos, then last block per row does top-k + finalize
__global__ __launch_bounds__(256) void k2_fused(
    const float* __restrict__ loc_pred, const float* __restrict__ cls_pred,
    const float* __restrict__ gt_boxes, const int* __restrict__ gt_labels,
    const float* __restrict__ dboxes, const unsigned int* __restrict__ packed,
    const unsigned long long* __restrict__ dpg, float* __restrict__ ce_neg,
    float* __restrict__ rowacc, unsigned int* __restrict__ rowdone,
    float* __restrict__ gsum, int* __restrict__ gnpos,
    unsigned int* __restrict__ done, float* __restrict__ out) {
  __shared__ K2Shared u;
  __shared__ int s_lab[MM];
  __shared__ float s_gt[MM][4];
  __shared__ int s_ov[K2_CELLS];   // force-match override: 0 = none, else m+1
  __shared__ float s_rf[4], s_rl[4];
  __shared__ int s_ri[4];
  __shared__ int s_lastf, s_np;

  const int b = blockIdx.y;
  const int d0 = blockIdx.x * K2_CELLS;
  const int tid = threadIdx.x;
  const int lane = tid & 63, wid = tid >> 6;
  const int ncell = min(K2_CELLS, DD - d0);
  const int nflt = ncell * CC;
  const float* srcf = cls_pred + ((size_t)b * DD + d0) * CC;  // 16B-aligned
  const int nv4 = nflt >> 2;
  for (int i = tid; i < nv4; i += 256) u.cls4[i] = ((const float4*)srcf)[i];
  for (int i = (nv4 << 2) + tid; i < nflt; i += 256) u.cls[i] = srcf[i];
  s_ov[tid] = 0;

  int dstar = -1;
  if (tid < MM) {
    dstar = (int)(0xFFFFFFFFu - (unsigned)(dpg[(size_t)b * MM + tid] & 0xFFFFFFFFull));
    s_lab[tid] = gt_labels[b * MM + tid];
    const float4 g = *(const float4*)(gt_boxes + ((size_t)b * MM + tid) * 4);
    s_gt[tid][0] = g.x; s_gt[tid][1] = g.y; s_gt[tid][2] = g.z; s_gt[tid][3] = g.w;
  }
  __syncthreads();
  if (tid < MM) {
    const int ds = dstar - d0;
    if (ds >= 0 && ds < K2_CELLS) atomicMax(&s_ov[ds], tid + 1);  // max m = last wins
  }
  __syncthreads();

  float ce_pos = 0.0f, sl1 = 0.0f; int posc = 0;
  if (tid < ncell) {
    const int d = d0 + tid;
    const unsigned p = packed[(size_t)b * DD + d];
    int bm = (int)(p & 255u), lab = (int)(p >> 8);
    const int ov = s_ov[tid];
    if (ov) { bm = ov - 1; lab = s_lab[bm]; }
    const float* x = &u.cls[tid * CC];
    float mx = x[0];
#pragma unroll
    for (int c = 1; c < CC; ++c) mx = fmaxf(mx, x[c]);
    float se = 0.0f;
#pragma unroll
    for (int c = 0; c < CC; ++c) se = __fadd_rn(se, __expf(__fsub_rn(x[c], mx)));
    const float ce = __fsub_rn(__fadd_rn(mx, __logf(se)), x[lab]);
    const bool pos = lab > 0;
    ce_neg[(size_t)b * DD + d] = pos ? -1.0f : ce;
    if (pos) {
      posc = 1; ce_pos = ce;
      const float4 lp = *(const float4*)(loc_pred + ((size_t)b * DD + d) * 4);
      const float4 pr = *(const float4*)(dboxes + (size_t)d * 4);  // cx cy w h
      const float gx1 = s_gt[bm][0], gy1 = s_gt[bm][1];
      const float gx2 = s_gt[bm][2], gy2 = s_gt[bm][3];
      const float gcx = __fmul_rn(__fadd_rn(gx1, gx2), 0.5f);
      const float gcy = __fmul_rn(__fadd_rn(gy1, gy2), 0.5f);
      const float gw = __fsub_rn(gx2, gx1), gh = __fsub_rn(gy2, gy1);
      const float t0 = __fdiv_rn(__fsub_rn(gcx, pr.x), __fdiv_rn(pr.z, 10.0f));
      const float t1 = __fdiv_rn(__fsub_rn(gcy, pr.y), __fdiv_rn(pr.w, 10.0f));
      const float t2 = __fmul_rn(__logf(__fdiv_rn(gw, pr.z)), 5.0f);
      const float t3 = __fmul_rn(__logf(__fdiv_rn(gh, pr.w)), 5.0f);
      float dv, ad;
      dv = __fsub_rn(lp.x, t0); ad = fabsf(dv);
      sl1 += (ad < 1.0f) ? __fmul_rn(0.5f, __fmul_rn(dv, dv)) : __fsub_rn(ad, 0.5f);
      dv = __fsub_rn(lp.y, t1); ad = fabsf(dv);
      sl1 += (ad < 1.0f) ? __fmul_rn(0.5f, __fmul_rn(dv, dv)) : __fsub_rn(ad, 0.5f);
      dv = __fsub_rn(lp.z, t2); ad = fabsf(dv);
      sl1 += (ad < 1.0f) ? __fmul_rn(0.5f, __fmul_rn(dv, dv)) : __fsub_rn(ad, 0.5f);
      dv = __fsub_rn(lp.w, t3); ad = fabsf(dv);
      sl1 += (ad < 1.0f) ? __fmul_rn(0.5f, __fmul_rn(dv, dv)) : __fsub_rn(ad, 0.5f);
    }
  }
  const float cs = wave_sum_f(ce_pos);
  const float ls = wave_sum_f(sl1);
  const int ps = wave_sum_i(posc);
  if (lane == 0) { s_rf[wid] = cs; s_rl[wid] = ls; s_ri[wid] = ps; }
  __syncthreads();
  float* row = rowacc + b * ROW_STRIDE;
  if (tid == 0) {
    const float c = s_rf[0] + s_rf[1] + s_rf[2] + s_rf[3];
    const float l = s_rl[0] + s_rl[1] + s_rl[2] + s_rl[3];
    const int p2 = s_ri[0] + s_ri[1] + s_ri[2] + s_ri[3];
    atomicAdd(&row[0], c);
    atomicAdd(&row[1], l);
    if (p2) atomicAdd((int*)&row[2], p2);
    // arrival: release own writes, acquire everyone else's if last
    int lastf = 0;
    __threadfence();
    if (atomicAdd(&rowdone[b], 1u) == K2_NBLK - 1) {
      __threadfence();
      lastf = 1;
      s_np = ((const int*)row)[2];
    }
    s_lastf = lastf;
  }
  __syncthreads();
  if (!s_lastf) return;

  // ---------------- tail: top-k negatives for row b (radix-256 select) -------
  const int np = s_np;
  const int k = min(3 * np, DD - np);
  const float* cerow = ce_neg + (size_t)b * DD;
  unsigned key[K2T_PER];
#pragma unroll
  for (int i = 0; i < K2T_PER; ++i) {
    const int d = tid + i * K2_CELLS;
    unsigned uu = 0xFF800000u;                 // -inf for pad
    if (d < DD) uu = __float_as_uint(cerow[d]);
    key[i] = (uu & 0x80000000u) ? ~uu : (uu | 0x80000000u);  // sortable key
  }

  unsigned T = 0u; int kk = k; float topk = 0.0f;
  if (k > 0) {
    for (int r = 0; r < 4; ++r) {
      const int shift = 24 - 8 * r;
      const unsigned pmask = (r == 0) ? 0u : (0xFFFFFFFFu << (32 - 8 * r));
      for (int i = tid; i < 16 * 256; i += 256) u.r.hist[i] = 0;
      __syncthreads();
      int* h = u.r.hist + ((tid & 15) << 8);   // 16 sub-hists to spread LDS atomics
      const unsigned want = T & pmask;
#pragma unroll
      for (int i = 0; i < K2T_PER; ++i)
        if ((key[i] & pmask) == want) atomicAdd(&h[(key[i] >> shift) & 255], 1);
      __syncthreads();
      int bt = 0;
#pragma unroll
      for (int s2 = 0; s2 < 16; ++s2) bt += u.r.hist[(s2 << 8) + tid];
      u.r.bin[tid] = bt;
      __syncthreads();
      if (tid < 64) {  // wave 0: descending suffix-scan over 256 bins (4/lane)
        const int h0 = u.r.bin[4 * tid], h1 = u.r.bin[4 * tid + 1];
        const int h2 = u.r.bin[4 * tid + 2], h3 = u.r.bin[4 * tid + 3];
        const int gsv = h0 + h1 + h2 + h3;
        int sfx = gsv;
#pragma unroll
        for (int o = 1; o < 64; o <<= 1) {
          const int x = __shfl_down(sfx, o, 64);
          if (tid + o < 64) sfx += x;
        }
        const int above = sfx - gsv;           // count in bins above my group
        if (sfx >= kk && above < kk) {         // boundary lane (exactly one)
          const int c3 = above + h3, c2 = c3 + h2, c1 = c2 + h1;
          int v, cgt;
          if (c3 >= kk)      { v = 3; cgt = above; }
          else if (c2 >= kk) { v = 2; cgt = c3; }
          else if (c1 >= kk) { v = 1; cgt = c2; }
          else               { v = 0; cgt = c1; }
          u.r.sel[0] = (tid << 2) + v;
          u.r.sel[1] = kk - cgt;
        }
      }
      __syncthreads();
      T |= ((unsigned)u.r.sel[0]) << shift;
      kk = u.r.sel[1];
    }
    // sum strictly-greater values; remainder kk are ties at T
    float sv = 0.0f;
#pragma unroll
    for (int i = 0; i < K2T_PER; ++i)
      if (key[i] > T) sv += __uint_as_float(key[i] ^ 0x80000000u);
    sv = wave_sum_f(sv);
    if (lane == 0) s_rf[wid] = sv;
    __syncthreads();
    if (tid == 0) {
      const float vT = (T & 0x80000000u) ? __uint_as_float(T ^ 0x80000000u)
                                         : __uint_as_float(~T);
      topk = (s_rf[0] + s_rf[1] + s_rf[2] + s_rf[3]) + (float)kk * vT;
    }
  }
  if (tid == 0) {
    atomicAdd(gsum, row[0] + row[1] + topk);
    atomicAdd(gnpos, np);
    __threadfence();
    if (atomicAdd(done, 1u) == BB - 1) {  // last row: finalize
      const float total = atomicAdd(gsum, 0.0f);
      const int npt = atomicAdd(gnpos, 0);
      out[0] = __fdiv_rn(total, (float)((npt > 0) ? npt : 1));
    }
  }
}

extern "C" void kernel_launch(void* const* d_in, const int* in_sizes, int n_in,
                              void* d_out, int out_size, void* d_ws, size_t ws_size,
                              hipStream_t stream) {
  const float* loc_pred = (const float*)d_in[0];
  const float* cls_pred = (const float*)d_in[1];
  const float* gt_boxes = (const float*)d_in[2];
  const int* gt_labels = (const int*)d_in[3];
  const float* dboxes = (const float*)d_in[4];

  char* ws = (char*)d_ws;
  unsigned long long* dpg = (unsigned long long*)(ws + WS_DPG);
  float* rowacc = (float*)(ws + WS_ROW);
  float* gsum = (float*)(ws + WS_GSUM);
  int* gnpos = (int*)(ws + WS_GNPOS);
  unsigned int* done = (unsigned int*)(ws + WS_DONE);
  unsigned int* rowdone = (unsigned int*)(ws + WS_RDONE);
  unsigned int* packed = (unsigned int*)(ws + WS_PACKED);
  float* ce_neg = (float*)(ws + WS_CENEG);

  hipMemsetAsync(ws, 0, WS_ZERO_BYTES, stream);

  k1_match<<<dim3(K1_NCH, BB), 256, 0, stream>>>(gt_boxes, gt_labels, dboxes,
                                                 packed, dpg);
  k2_fused<<<dim3(K2_NBLK, BB), 256, 0, stream>>>(loc_pred, cls_pred, gt_boxes,
                                                  gt_labels, dboxes, packed, dpg,
                                                  ce_neg, rowacc, rowdone,
                                                  gsum, gnpos, done,
                                                  (float*)d_out);
}

// Round 3
// 225.640 us; speedup vs baseline: 1.9629x; 1.9629x over previous
//
#include <hip/hip_runtime.h>

#define BB 128
#define DD 8732
#define MM 32
#define CC 21

constexpr int K1_PR  = 4;                               // priors per thread
constexpr int K1_CH  = 256 * K1_PR;                     // 1024 priors per block
constexpr int K1_NCH = (DD + K1_CH - 1) / K1_CH;        // 9 chunks
constexpr int K2_CELLS = 256;
constexpr int K2_NBLK  = (DD + K2_CELLS - 1) / K2_CELLS; // 35 blocks per row
constexpr int K2B_T    = 1024;                           // k2b block size
constexpr int K2B_PER  = (DD + K2B_T - 1) / K2B_T;       // 9 keys per thread
constexpr int K2B_W    = K2B_T / 64;                     // 16 waves
constexpr int K2B_SH   = 32;                             // LDS sub-histograms

// ---- workspace layout (bytes) ----
constexpr size_t WS_DPG    = 0;                          // B*M u64 atomicMax keys (32768 B)
constexpr size_t WS_ROW    = 32768;                      // B rows * 64 B: [0]=conf f32, [1]=loc f32, [2]=npos i32
constexpr int    ROW_STRIDE = 16;                        // floats per row slot (64 B)
constexpr size_t WS_GSUM   = 40960;                      // f32, own line
constexpr size_t WS_GNPOS  = 41088;                      // i32, own line
constexpr size_t WS_DONE   = 41216;                      // u32, own line
constexpr size_t WS_ZERO_BYTES = 41344;                  // memset region
constexpr size_t WS_PACKED = 41472;                      // B*D u32 (lab<<8|bm)
constexpr size_t WS_CENEG  = WS_PACKED + (size_t)BB * DD * 4; // B*D f32

__device__ __forceinline__ float wave_sum_f(float v) {
#pragma unroll
  for (int o = 32; o > 0; o >>= 1) v += __shfl_xor(v, o, 64);
  return v;
}
__device__ __forceinline__ int wave_sum_i(int v) {
#pragma unroll
  for (int o = 32; o > 0; o >>= 1) v += __shfl_xor(v, o, 64);
  return v;
}

// ---------------- K1: matching ----------------
__global__ __launch_bounds__(256) void k1_match(
    const float* __restrict__ gt_boxes, const int* __restrict__ gt_labels,
    const float* __restrict__ dboxes,
    unsigned int* __restrict__ packed, unsigned long long* __restrict__ dpg) {
  __shared__ float s_gx1[MM], s_gy1[MM], s_gx2[MM], s_gy2[MM], s_ga[MM];
  __shared__ int s_gl[MM];
  __shared__ unsigned long long s_pm[MM * 4];

  const int b = blockIdx.y;
  const int tid = threadIdx.x;
  if (tid < MM) {
    const float* g = gt_boxes + ((size_t)b * MM + tid) * 4;
    const float x1 = g[0], y1 = g[1], x2 = g[2], y2 = g[3];
    s_gx1[tid] = x1; s_gy1[tid] = y1; s_gx2[tid] = x2; s_gy2[tid] = y2;
    s_ga[tid] = __fmul_rn(__fsub_rn(x2, x1), __fsub_rn(y2, y1));
    s_gl[tid] = gt_labels[b * MM + tid];
  }
  __syncthreads();

  float px1[K1_PR], py1[K1_PR], px2[K1_PR], py2[K1_PR], pa[K1_PR];
  int dd[K1_PR];
  const int dbase = blockIdx.x * K1_CH + tid;
#pragma unroll
  for (int i = 0; i < K1_PR; ++i) {
    const int d = dbase + i * 256;
    if (d < DD) {
      const float4 p = *(const float4*)(dboxes + (size_t)d * 4);
      const float hw = __fmul_rn(p.z, 0.5f), hh = __fmul_rn(p.w, 0.5f);
      px1[i] = __fsub_rn(p.x, hw); py1[i] = __fsub_rn(p.y, hh);
      px2[i] = __fadd_rn(p.x, hw); py2[i] = __fadd_rn(p.y, hh);
      pa[i] = __fmul_rn(__fsub_rn(px2[i], px1[i]), __fsub_rn(py2[i], py1[i]));
      dd[i] = d;
    } else {  // pad: iou=0, can never win ties (huge d)
      px1[i] = 3e9f; py1[i] = 3e9f; px2[i] = 3e9f; py2[i] = 3e9f; pa[i] = 1.0f;
      dd[i] = 0x7FFFFFFF;
    }
  }

  float vb[K1_PR]; int mb[K1_PR];
#pragma unroll
  for (int i = 0; i < K1_PR; ++i) { vb[i] = -1.0f; mb[i] = 0; }

  const int lane = tid & 63, wid = tid >> 6;
  for (int m = 0; m < MM; ++m) {
    const float gx1 = s_gx1[m], gy1 = s_gy1[m], gx2 = s_gx2[m], gy2 = s_gy2[m];
    const float ga = s_ga[m];
    float mv = -1.0f; int md = 0x7FFFFFFF;
#pragma unroll
    for (int i = 0; i < K1_PR; ++i) {
      // exact (non-contracted) f32 to match numpy bit-for-bit
      const float w = fmaxf(0.0f, __fsub_rn(fminf(gx2, px2[i]), fmaxf(gx1, px1[i])));
      const float h = fmaxf(0.0f, __fsub_rn(fminf(gy2, py2[i]), fmaxf(gy1, py1[i])));
      const float inter = __fmul_rn(w, h);
      const float den = __fsub_rn(__fadd_rn(ga, pa[i]), inter);
      const float val = __fdiv_rn(inter, den);
      if (val > vb[i]) { vb[i] = val; mb[i] = m; }   // strict >: first m wins
      if (val > mv) { mv = val; md = dd[i]; }        // d ascending: first d wins
    }
    // split reduction: f32-max butterfly, then min-d among exact-max ties
    float mva = mv;
#pragma unroll
    for (int o = 32; o > 0; o >>= 1) mva = fmaxf(mva, __shfl_xor(mva, o, 64));
    int mdm = (mv == mva) ? md : 0x7FFFFFFF;
#pragma unroll
    for (int o = 32; o > 0; o >>= 1) mdm = min(mdm, __shfl_xor(mdm, o, 64));
    if (lane == 0)
      s_pm[m * 4 + wid] =
          (((unsigned long long)__float_as_uint(mva)) << 32) |
          (unsigned long long)(0xFFFFFFFFu - (unsigned)mdm);
  }
  __syncthreads();
  if (tid < MM) {
    unsigned long long k0 = s_pm[tid * 4 + 0];
    if (s_pm[tid * 4 + 1] > k0) k0 = s_pm[tid * 4 + 1];
    if (s_pm[tid * 4 + 2] > k0) k0 = s_pm[tid * 4 + 2];
    if (s_pm[tid * 4 + 3] > k0) k0 = s_pm[tid * 4 + 3];
    atomicMax(&dpg[b * MM + tid], k0);
  }
#pragma unroll
  for (int i = 0; i < K1_PR; ++i) {
    if (dd[i] < DD) {
      const int lab = (vb[i] < 0.5f) ? 0 : s_gl[mb[i]];
      packed[(size_t)b * DD + dd[i]] = ((unsigned)lab << 8) | (unsigned)mb[i];
    }
  }
}

// ---------------- K2a: CE + loc loss + n_pos (per-row accumulators) -------
__global__ __launch_bounds__(256) void k2a_ce(
    const float* __restrict__ loc_pred, const float* __restrict__ cls_pred,
    const float* __restrict__ gt_boxes, const int* __restrict__ gt_labels,
    const float* __restrict__ dboxes, const unsigned int* __restrict__ packed,
    const unsigned long long* __restrict__ dpg, float* __restrict__ ce_neg,
    float* __restrict__ rowacc) {
  __shared__ float s_cls[K2_CELLS * CC];
  __shared__ int s_lab[MM];
  __shared__ float s_gt[MM][4];
  __shared__ int s_ov[K2_CELLS];   // force-match override: 0 = none, else m+1
  __shared__ float s_rf[4], s_rl[4];
  __shared__ int s_ri[4];

  const int b = blockIdx.y;
  const int d0 = blockIdx.x * K2_CELLS;
  const int tid = threadIdx.x;
  const int lane = tid & 63, wid = tid >> 6;
  const int ncell = min(K2_CELLS, DD - d0);
  const int nflt = ncell * CC;
  const float* srcf = cls_pred + ((size_t)b * DD + d0) * CC;  // 16B-aligned
  const int nv4 = nflt >> 2;
  for (int i = tid; i < nv4; i += 256)
    ((float4*)s_cls)[i] = ((const float4*)srcf)[i];
  for (int i = (nv4 << 2) + tid; i < nflt; i += 256) s_cls[i] = srcf[i];
  s_ov[tid] = 0;

  int dstar = -1;
  if (tid < MM) {
    dstar = (int)(0xFFFFFFFFu - (unsigned)(dpg[(size_t)b * MM + tid] & 0xFFFFFFFFull));
    s_lab[tid] = gt_labels[b * MM + tid];
    const float4 g = *(const float4*)(gt_boxes + ((size_t)b * MM + tid) * 4);
    s_gt[tid][0] = g.x; s_gt[tid][1] = g.y; s_gt[tid][2] = g.z; s_gt[tid][3] = g.w;
  }
  __syncthreads();
  if (tid < MM) {
    const int ds = dstar - d0;
    if (ds >= 0 && ds < K2_CELLS) atomicMax(&s_ov[ds], tid + 1);  // max m = last wins
  }
  __syncthreads();

  float ce_pos = 0.0f, sl1 = 0.0f; int posc = 0;
  if (tid < ncell) {
    const int d = d0 + tid;
    const unsigned p = packed[(size_t)b * DD + d];
    int bm = (int)(p & 255u), lab = (int)(p >> 8);
    const int ov = s_ov[tid];
    if (ov) { bm = ov - 1; lab = s_lab[bm]; }
    const float* x = &s_cls[tid * CC];
    float mx = x[0];
#pragma unroll
    for (int c = 1; c < CC; ++c) mx = fmaxf(mx, x[c]);
    float se = 0.0f;
#pragma unroll
    for (int c = 0; c < CC; ++c) se = __fadd_rn(se, __expf(__fsub_rn(x[c], mx)));
    const float ce = __fsub_rn(__fadd_rn(mx, __logf(se)), x[lab]);
    const bool pos = lab > 0;
    ce_neg[(size_t)b * DD + d] = pos ? -1.0f : ce;
    if (pos) {
      posc = 1; ce_pos = ce;
      const float4 lp = *(const float4*)(loc_pred + ((size_t)b * DD + d) * 4);
      const float4 pr = *(const float4*)(dboxes + (size_t)d * 4);  // cx cy w h
      const float gx1 = s_gt[bm][0], gy1 = s_gt[bm][1];
      const float gx2 = s_gt[bm][2], gy2 = s_gt[bm][3];
      const float gcx = __fmul_rn(__fadd_rn(gx1, gx2), 0.5f);
      const float gcy = __fmul_rn(__fadd_rn(gy1, gy2), 0.5f);
      const float gw = __fsub_rn(gx2, gx1), gh = __fsub_rn(gy2, gy1);
      const float t0 = __fdiv_rn(__fsub_rn(gcx, pr.x), __fdiv_rn(pr.z, 10.0f));
      const float t1 = __fdiv_rn(__fsub_rn(gcy, pr.y), __fdiv_rn(pr.w, 10.0f));
      const float t2 = __fmul_rn(__logf(__fdiv_rn(gw, pr.z)), 5.0f);
      const float t3 = __fmul_rn(__logf(__fdiv_rn(gh, pr.w)), 5.0f);
      float dv, ad;
      dv = __fsub_rn(lp.x, t0); ad = fabsf(dv);
      sl1 += (ad < 1.0f) ? __fmul_rn(0.5f, __fmul_rn(dv, dv)) : __fsub_rn(ad, 0.5f);
      dv = __fsub_rn(lp.y, t1); ad = fabsf(dv);
      sl1 += (ad < 1.0f) ? __fmul_rn(0.5f, __fmul_rn(dv, dv)) : __fsub_rn(ad, 0.5f);
      dv = __fsub_rn(lp.z, t2); ad = fabsf(dv);
      sl1 += (ad < 1.0f) ? __fmul_rn(0.5f, __fmul_rn(dv, dv)) : __fsub_rn(ad, 0.5f);
      dv = __fsub_rn(lp.w, t3); ad = fabsf(dv);
      sl1 += (ad < 1.0f) ? __fmul_rn(0.5f, __fmul_rn(dv, dv)) : __fsub_rn(ad, 0.5f);
    }
  }
  const float cs = wave_sum_f(ce_pos);
  const float ls = wave_sum_f(sl1);
  const int ps = wave_sum_i(posc);
  if (lane == 0) { s_rf[wid] = cs; s_rl[wid] = ls; s_ri[wid] = ps; }
  __syncthreads();
  if (tid == 0) {
    const float c = s_rf[0] + s_rf[1] + s_rf[2] + s_rf[3];
    const float l = s_rl[0] + s_rl[1] + s_rl[2] + s_rl[3];
    const int p = s_ri[0] + s_ri[1] + s_ri[2] + s_ri[3];
    float* row = rowacc + b * ROW_STRIDE;   // 64-B private slot for row b
    atomicAdd(&row[0], c);
    atomicAdd(&row[1], l);
    if (p) atomicAdd((int*)&row[2], p);
  }
}

// ---------------- K2b: per-row top-k negatives (radix-256 select) ----------
__global__ __launch_bounds__(K2B_T) void k2b_topk(
    const float* __restrict__ ce_neg, const float* __restrict__ rowacc,
    float* __restrict__ gsum, int* __restrict__ gnpos,
    unsigned int* __restrict__ done, float* __restrict__ out) {
  __shared__ int s_hist[K2B_SH * 256];    // 32 KB: sub-hists spread hot-bin atomics
  __shared__ int s_bin[256];
  __shared__ int s_sel[2];
  __shared__ float s_rf[K2B_W];
  const int b = blockIdx.x;
  const int tid = threadIdx.x;
  const int lane = tid & 63, wid = tid >> 6;
  const float* row = rowacc + b * ROW_STRIDE;
  const int np = ((const int*)row)[2];
  const int k = min(3 * np, DD - np);

  unsigned key[K2B_PER];
#pragma unroll
  for (int i = 0; i < K2B_PER; ++i) {
    const int d = tid + i * K2B_T;
    unsigned uu = 0xFF800000u;                 // -inf for pad: lowest key
    if (d < DD) uu = __float_as_uint(ce_neg[(size_t)b * DD + d]);
    key[i] = (uu & 0x80000000u) ? ~uu : (uu | 0x80000000u);  // sortable key
  }

  float topk = 0.0f;
  if (k > 0) {
    unsigned T = 0u; int kk = k;
    for (int r = 0; r < 4; ++r) {
      const int shift = 24 - 8 * r;
      const unsigned pmask = (r == 0) ? 0u : (0xFFFFFFFFu << (32 - 8 * r));
      for (int i = tid; i < K2B_SH * 256; i += K2B_T) s_hist[i] = 0;
      __syncthreads();
      int* h = s_hist + ((tid & (K2B_SH - 1)) << 8);
      const unsigned want = T & pmask;
#pragma unroll
      for (int i = 0; i < K2B_PER; ++i)
        if ((key[i] & pmask) == want) atomicAdd(&h[(key[i] >> shift) & 255], 1);
      __syncthreads();
      if (tid < 256) {
        int bt = 0;
#pragma unroll
        for (int s2 = 0; s2 < K2B_SH; ++s2) bt += s_hist[(s2 << 8) + tid];
        s_bin[tid] = bt;
      }
      __syncthreads();
      if (tid < 64) {  // wave 0: descending suffix-scan over 256 bins (4/lane)
        const int h0 = s_bin[4 * tid], h1 = s_bin[4 * tid + 1];
        const int h2 = s_bin[4 * tid + 2], h3 = s_bin[4 * tid + 3];
        const int gsv = h0 + h1 + h2 + h3;
        int sfx = gsv;
#pragma unroll
        for (int o = 1; o < 64; o <<= 1) {
          const int x = __shfl_down(sfx, o, 64);
          if (tid + o < 64) sfx += x;
        }
        const int above = sfx - gsv;           // count in bins above my group
        if (sfx >= kk && above < kk) {         // boundary lane (exactly one)
          const int c3 = above + h3, c2 = c3 + h2, c1 = c2 + h1;
          int v, cgt;
          if (c3 >= kk)      { v = 3; cgt = above; }
          else if (c2 >= kk) { v = 2; cgt = c3; }
          else if (c1 >= kk) { v = 1; cgt = c2; }
          else               { v = 0; cgt = c1; }
          s_sel[0] = (tid << 2) + v;
          s_sel[1] = kk - cgt;
        }
      }
      __syncthreads();
      T |= ((unsigned)s_sel[0]) << shift;
      kk = s_sel[1];
      __syncthreads();
    }
    // T = exact k-th largest key; kk ties at T included
    float sv = 0.0f;
#pragma unroll
    for (int i = 0; i < K2B_PER; ++i)
      if (key[i] > T) sv += __uint_as_float(key[i] ^ 0x80000000u);
    sv = wave_sum_f(sv);
    if (lane == 0) s_rf[wid] = sv;
    __syncthreads();
    if (tid == 0) {
      float sg = 0.0f;
#pragma unroll
      for (int w = 0; w < K2B_W; ++w) sg += s_rf[w];
      const float vT = (T & 0x80000000u) ? __uint_as_float(T ^ 0x80000000u)
                                         : __uint_as_float(~T);
      topk = sg + (float)kk * vT;
    }
  }
  if (tid == 0) {
    atomicAdd(gsum, row[0] + row[1] + topk);
    atomicAdd(gnpos, np);
    __threadfence();
    const unsigned old = atomicAdd(done, 1u);
    if (old == BB - 1) {  // last row: finalize
      const float total = atomicAdd(gsum, 0.0f);
      const int npt = atomicAdd(gnpos, 0);
      out[0] = __fdiv_rn(total, (float)((npt > 0) ? npt : 1));
    }
  }
}

extern "C" void kernel_launch(void* const* d_in, const int* in_sizes, int n_in,
                              void* d_out, int out_size, void* d_ws, size_t ws_size,
                              hipStream_t stream) {
  const float* loc_pred = (const float*)d_in[0];
  const float* cls_pred = (const float*)d_in[1];
  const float* gt_boxes = (const float*)d_in[2];
  const int* gt_labels = (const int*)d_in[3];
  const float* dboxes = (const float*)d_in[4];

  char* ws = (char*)d_ws;
  unsigned long long* dpg = (unsigned long long*)(ws + WS_DPG);
  float* rowacc = (float*)(ws + WS_ROW);
  float* gsum = (float*)(ws + WS_GSUM);
  int* gnpos = (int*)(ws + WS_GNPOS);
  unsigned int* done = (unsigned int*)(ws + WS_DONE);
  unsigned int* packed = (unsigned int*)(ws + WS_PACKED);
  float* ce_neg = (float*)(ws + WS_CENEG);

  hipMemsetAsync(ws, 0, WS_ZERO_BYTES, stream);

  k1_match<<<dim3(K1_NCH, BB), 256, 0, stream>>>(gt_boxes, gt_labels, dboxes,
                                                 packed, dpg);
  k2a_ce<<<dim3(K2_NBLK, BB), 256, 0, stream>>>(loc_pred, cls_pred, gt_boxes,
                                                gt_labels, dboxes, packed, dpg,
                                                ce_neg, rowacc);
  k2b_topk<<<BB, K2B_T, 0, stream>>>(ce_neg, rowacc, gsum, gnpos, done,
                                     (float*)d_out);
}